// Round 7
// baseline (631.597 us; speedup 1.0000x reference)
//
#include <hip/hip_runtime.h>
#include <stdint.h>
#include <stddef.h>

// MLA prefill: B=2,S=2048,D=2048,H=16,DH=128,DR=64,DCKV=512,DCQ=1536
#define BB 2
#define SS 2048
#define DD 2048
#define HH 16
#define DHH 128
#define DRR 64
#define DCKV 512
#define DCQ 1536

typedef __attribute__((ext_vector_type(8))) short short8;
typedef __attribute__((ext_vector_type(4))) short short4v;
typedef __attribute__((ext_vector_type(4))) float f32x4;
typedef unsigned int u32;

__device__ __forceinline__ short f2bf(float x) {
  unsigned u = __float_as_uint(x);
  u += 0x7fffu + ((u >> 16) & 1u);   // RNE
  return (short)(u >> 16);
}
__device__ __forceinline__ float bf2f(short s) {
  return __uint_as_float(((unsigned)(unsigned short)s) << 16);
}

// async global->LDS, 16B/lane: lds dest = wave-uniform base + lane*16.
__device__ __forceinline__ void gl2lds16(const short* g, short* l) {
  __builtin_amdgcn_global_load_lds(
      (const __attribute__((address_space(1))) u32*)g,
      (__attribute__((address_space(3))) u32*)l, 16, 0, 0);
}

// ---------------- cast fp32 -> bf16, x4 vectorized ----------------
__global__ __launch_bounds__(256) void cast_bf16_kernel(const float* __restrict__ in,
                                                        short* __restrict__ out, int n4) {
  int i = blockIdx.x * 256 + threadIdx.x;
  if (i >= n4) return;
  f32x4 f = ((const f32x4*)in)[i];
  short4v o;
  o[0] = f2bf(f[0]); o[1] = f2bf(f[1]); o[2] = f2bf(f[2]); o[3] = f2bf(f[3]);
  ((short4v*)out)[i] = o;
}

// ---------------- concat biases into cb1[3072], cb2[3072], cb3[4096] ----------------
__global__ __launch_bounds__(256) void concat_bias_kernel(
    const float* bkd, const float* bqd, const float* bkr,
    const float* bqu, const float* bqr, const float* bku, const float* bvu,
    float* cb1, float* cb2, float* cb3) {
  int idx = blockIdx.x * 256 + threadIdx.x;
  if (idx < 3072) {
    cb1[idx] = idx < 512 ? bkd[idx] : (idx < 2048 ? bqd[idx - 512] : bkr[idx - 2048]);
  } else if (idx < 6144) {
    int j = idx - 3072;
    cb2[j] = j < 2048 ? bqu[j] : bqr[j - 2048];
  } else if (idx < 10240) {
    int j = idx - 6144;
    cb3[j] = j < 2048 ? bku[j] : bvu[j - 2048];
  }
}

// ---------------- C[M,N] = A[M,K] @ B[N,K]^T + bias ----------------
// m97 structure: global_load_lds width-16 staging (linear LDS [row][32]),
// 2-barrier K-loop, 128x128 tile, BK=32, 4 waves (2x2 of 64x64).
// MODE 0: bf16 row-major.  MODE 1: f32 row-major.
// MODE 2: col<2048 scatter to qfull[B,H,S,192]; col>=2048 -> out2[row*1024+col-2048].
// MODE 3: col<2048 scatter to kfull[B,H,S,192]; col>=2048 -> FUSED TRANSPOSE into
//         vt[B,H,DH,S] (packed short4 along S) — replaces transpose_v pass.
template<int MODE>
__global__ __launch_bounds__(256) void gemm_bt(const short* __restrict__ A, int lda,
                                               const short* __restrict__ Bm, int ldb,
                                               const float* __restrict__ bias,
                                               void* __restrict__ Cout, void* __restrict__ out2,
                                               int M, int N, int K) {
  __shared__ __align__(16) short sA[128 * 32];
  __shared__ __align__(16) short sB[128 * 32];
  const int tid = threadIdx.x;
  const int w = tid >> 6, L = tid & 63, quad = L >> 4, lc = L & 15;
  const int wm = w >> 1, wn = w & 1;
  const int tm = blockIdx.x * 128, tn = blockIdx.y * 128;
  const int lrow = L >> 2, lch = (L & 3) * 8;
  f32x4 acc[4][4] = {};
  const int nk = K >> 5;
  for (int kt = 0; kt < nk; ++kt) {
    const int k0 = kt << 5;
    __syncthreads();
    {
      int sub = w * 2;
      gl2lds16(A + (size_t)(tm + sub * 16 + lrow) * lda + k0 + lch, &sA[sub * 512]);
      gl2lds16(A + (size_t)(tm + sub * 16 + 16 + lrow) * lda + k0 + lch, &sA[sub * 512 + 512]);
      gl2lds16(Bm + (size_t)(tn + sub * 16 + lrow) * ldb + k0 + lch, &sB[sub * 512]);
      gl2lds16(Bm + (size_t)(tn + sub * 16 + 16 + lrow) * ldb + k0 + lch, &sB[sub * 512 + 512]);
    }
    __syncthreads();
    short8 af[4], bfr[4];
#pragma unroll
    for (int ms = 0; ms < 4; ++ms)
      af[ms] = *(const short8*)&sA[(wm * 64 + ms * 16 + lc) * 32 + quad * 8];
#pragma unroll
    for (int ns = 0; ns < 4; ++ns)
      bfr[ns] = *(const short8*)&sB[(wn * 64 + ns * 16 + lc) * 32 + quad * 8];
#pragma unroll
    for (int ms = 0; ms < 4; ++ms)
#pragma unroll
      for (int ns = 0; ns < 4; ++ns)
        acc[ms][ns] = __builtin_amdgcn_mfma_f32_16x16x32_bf16(af[ms], bfr[ns], acc[ms][ns], 0, 0, 0);
  }
#pragma unroll
  for (int ms = 0; ms < 4; ++ms) {
    int row = tm + wm * 64 + ms * 16 + quad * 4;
#pragma unroll
    for (int ns = 0; ns < 4; ++ns) {
      int col = tn + wn * 64 + ns * 16 + lc;
      float bv = bias[col];
      if (MODE == 3 && col >= 2048) {
        // V -> vt[B,H,DH,S] fused transpose. row%4==0, so 4 r-values are 4
        // consecutive s at fixed (h_,dh): pack one 8B store.
        int j = col - 2048, h_ = j >> 7, dh = j & 127;
        int b_ = row >> 11, s0 = row & 2047;
        short4v pk;
#pragma unroll
        for (int r = 0; r < 4; ++r) pk[r] = f2bf(acc[ms][ns][r] + bv);
        *(short4v*)((short*)out2 + (((size_t)(b_ * HH + h_)) * DHH + dh) * SS + s0) = pk;
      } else {
#pragma unroll
        for (int r = 0; r < 4; ++r) {
          float vv = acc[ms][ns][r] + bv;
          int rrow = row + r;
          if (MODE == 0)      ((short*)Cout)[(size_t)rrow * N + col] = f2bf(vv);
          else if (MODE == 1) ((float*)Cout)[(size_t)rrow * N + col] = vv;
          else {
            if (col < 2048) {  // content -> full[B,H,S,192] (block-uniform branch)
              int b_ = rrow >> 11, s_ = rrow & 2047, h_ = col >> 7, d_ = col & 127;
              ((short*)Cout)[(((size_t)(b_ * HH + h_)) * SS + s_) * 192 + d_] = f2bf(vv);
            } else {  // MODE 2 only
              ((short*)out2)[(size_t)rrow * 1024 + (col - 2048)] = f2bf(vv);
            }
          }
        }
      }
    }
  }
}

// ------------- RoPE (rotate-half) into full[...,128:192]; strided bf16 src -------------
__global__ __launch_bounds__(256) void rope_kernel(const short* __restrict__ rin,
                                                   int rstride, int roff,
                                                   short* __restrict__ full) {
  int idx = blockIdx.x * 256 + threadIdx.x;  // B*S*H*32 threads
  int i = idx & 31, h = (idx >> 5) & 15, s = (idx >> 9) & 2047, b = idx >> 20;
  const short* base = rin + ((size_t)(b * SS + s)) * rstride + roff + h * DRR;
  float t1 = bf2f(base[i]), t2 = bf2f(base[i + 32]);
  float invf = expf(-9.210340371976184f * (float)i * (1.0f / 32.0f));  // 10000^(-i/32)
  float ang = (float)s * invf;
  float c = cosf(ang), sn = sinf(ang);
  short* ob = full + (((size_t)(b * HH + h)) * SS + s) * 192 + 128;
  ob[i]      = f2bf(t1 * c - t2 * sn);
  ob[i + 32] = f2bf(t1 * sn + t2 * c);
}

__device__ __forceinline__ float quad_max(float v) {
  v = fmaxf(v, __shfl_xor(v, 1));
  v = fmaxf(v, __shfl_xor(v, 2));
  v = fmaxf(v, __shfl_xor(v, 4));
  v = fmaxf(v, __shfl_xor(v, 8));
  return v;
}
__device__ __forceinline__ float quad_sum(float v) {
  v += __shfl_xor(v, 1); v += __shfl_xor(v, 2);
  v += __shfl_xor(v, 4); v += __shfl_xor(v, 8);
  return v;
}

// ------------- flash attention, SPLIT-K, 4-blocks/CU (R7) -------------
// R6 post-mortem: 4 schedules all ~8-9% MfmaUtil, T_iter ~20k cy with only
// ~2.5k cy of issue/wave — 75% stall with 1.4 waves/SIMD to hide it. LDS
// 56KB capped residency at 2 blocks/CU (8 waves); heavy chunks also launched
// LAST (worst tail). R7, two occupancy levers, both prior-verified patterns:
//  (1) P unioned into sK (R2 pattern): LDS 40KB -> 4 blocks/CU = 16 waves.
//      Costs a 3rd barrier (QK sK-reads must finish before P overwrites).
//  (2) heavy-first dispatch: reverse chunk order (159-(bid>>3), bijective) so
//      8-iter chunks start first and 1-2-iter chunks drain the tail.
// K/V staging, swizzles, mask, softmax, epilogue, combine all R6-verified.
__global__ __launch_bounds__(256, 2) void mla_flash_kernel(const short* __restrict__ Qf,
                                                           const short* __restrict__ Kf,
                                                           const short* __restrict__ Vt,
                                                           float* __restrict__ Opart,
                                                           float* __restrict__ Mpart,
                                                           float* __restrict__ Lpart,
                                                           short* __restrict__ attn) {
  const int bid = blockIdx.x;
  const int g0 = (bid & 7) * 160 + (159 - (bid >> 3));  // heavy-first within XCD group
  const int bh = g0 / 40, xc = g0 - bh * 40;
  int qt, c;
  if (xc < 4)       { qt = xc;                  c = 0; }
  else if (xc < 12) { qt = 4 + ((xc - 4) >> 1);  c = (xc - 4) & 1; }
  else if (xc < 24) { qt = 8 + (xc - 12) / 3;    c = (xc - 12) % 3; }
  else              { qt = 12 + ((xc - 24) >> 2); c = (xc - 24) & 3; }
  const int nc = (qt + 4) >> 2;                 // chunks for this qt
  const int k8 = c * 8;                         // k-range in 64-col units
  const int klim = 2 * qt + 2;
  const int kend = (k8 + 8 < klim) ? k8 + 8 : klim;
  const int slot = bh * 40 + xc;                // compact partial slot

  const int h = bh & 15, b = bh >> 4;
  const int tid = threadIdx.x, w = tid >> 6, L = tid & 63, quad = L >> 4, lc = L & 15;
  __shared__ __align__(16) short sK[12288];     // 64x192 bf16 (XOR-swizzled), 24KB
  __shared__ __align__(16) short sV[8192];      // V^T tile [128dh][64s] swizzled, 16KB
  short* Pf = sK;                               // P [128][64] (16KB) UNIONED over sK

  const short* Qb = Qf + ((size_t)bh) * SS * 192;
  const short* Kb = Kf + ((size_t)bh) * SS * 192;
  const short* Vb = Vt + ((size_t)bh) * DHH * SS;

  const int qrow0 = qt * 128 + w * 32;
  short8 qa[2][6];
#pragma unroll
  for (int ms = 0; ms < 2; ++ms)
#pragma unroll
    for (int kk = 0; kk < 6; ++kk)
      qa[ms][kk] = *(const short8*)(Qb + (size_t)(qrow0 + ms * 16 + lc) * 192 + kk * 32 + quad * 8);

  f32x4 O[2][8] = {};
  float mrow[2][4], lrow[2][4];
#pragma unroll
  for (int ms = 0; ms < 2; ++ms)
#pragma unroll
    for (int r = 0; r < 4; ++r) { mrow[ms][r] = -1e30f; lrow[ms][r] = 0.f; }

  // K staging map: thread stages row srow_=tid>>2, 16B chunk sq_=tid&3 of each
  // 32-col segment i (6 segs). Swizzled slot matches the QK read pattern.
  const int srow_ = tid >> 2, sq_ = tid & 3;
  const int sslot = srow_ * 4 + (sq_ ^ ((srow_ >> 1) & 3));
  // V staging map: thread stages rows j*32+(tid>>3), 16B chunk tid&7 (coalesced).
  const int vrow_ = tid >> 3, vch_ = tid & 7;
  short8 g[6], gv[4];
#pragma unroll
  for (int i = 0; i < 6; ++i)   // prologue: K tile k8
    g[i] = *(const short8*)(Kb + (size_t)(k8 * 64 + srow_) * 192 + i * 32 + sq_ * 8);
#pragma unroll
  for (int j = 0; j < 4; ++j)   // prologue: V tile k8
    gv[j] = *(const short8*)(Vb + (size_t)(j * 32 + vrow_) * SS + k8 * 64 + vch_ * 8);

  for (int kt = k8; kt < kend; ++kt) {
    __syncthreads();  // barrier A: all waves' prev-iter P(sK)/sV reads done
#pragma unroll
    for (int i = 0; i < 6; ++i)
      *(short8*)&sK[(i * 256 + sslot) * 8] = g[i];
#pragma unroll
    for (int j = 0; j < 4; ++j) {
      int row = j * 32 + vrow_;
      *(short8*)&sV[row * 64 + ((vch_ ^ (row & 7)) << 3)] = gv[j];
    }
    if (kt + 1 < kend) {   // issue next tile's loads; latency hides under body
#pragma unroll
      for (int i = 0; i < 6; ++i)
        g[i] = *(const short8*)(Kb + (size_t)((kt + 1) * 64 + srow_) * 192 + i * 32 + sq_ * 8);
#pragma unroll
      for (int j = 0; j < 4; ++j)
        gv[j] = *(const short8*)(Vb + (size_t)(j * 32 + vrow_) * SS + (kt + 1) * 64 + vch_ * 8);
    }
    __syncthreads();  // barrier B: staging visible
    // QK: 64 k-cols
    f32x4 sc[2][4] = {};
#pragma unroll
    for (int kk = 0; kk < 6; ++kk)
#pragma unroll
      for (int ns = 0; ns < 4; ++ns) {
        int rr = ns * 16 + lc;
        short8 kb = *(const short8*)&sK[(kk * 256 + rr * 4 + (quad ^ ((rr >> 1) & 3))) * 8];
        sc[0][ns] = __builtin_amdgcn_mfma_f32_16x16x32_bf16(qa[0][kk], kb, sc[0][ns], 0, 0, 0);
        sc[1][ns] = __builtin_amdgcn_mfma_f32_16x16x32_bf16(qa[1][kk], kb, sc[1][ns], 0, 0, 0);
      }
    const float scale = 0.07216878364870322f;  // 1/sqrt(192)
#pragma unroll
    for (int ms = 0; ms < 2; ++ms)
#pragma unroll
      for (int ns = 0; ns < 4; ++ns)
#pragma unroll
        for (int r = 0; r < 4; ++r) {
          float vv = sc[ms][ns][r] * scale;
          if (kt * 64 + ns * 16 + lc > qrow0 + ms * 16 + quad * 4 + r) vv = -1e30f;
          sc[ms][ns][r] = vv;
        }
    // online softmax; row (ms, quad*4+r) lives in this quad's 16 lanes
#pragma unroll
    for (int ms = 0; ms < 2; ++ms)
#pragma unroll
      for (int r = 0; r < 4; ++r) {
        float mx = fmaxf(fmaxf(sc[ms][0][r], sc[ms][1][r]), fmaxf(sc[ms][2][r], sc[ms][3][r]));
        mx = quad_max(mx);
        float mnew = fmaxf(mrow[ms][r], mx);
        float alpha = __expf(mrow[ms][r] - mnew);
        mrow[ms][r] = mnew;
        float ps = 0.f;
#pragma unroll
        for (int ns = 0; ns < 4; ++ns) {
          float p = __expf(sc[ms][ns][r] - mnew);
          sc[ms][ns][r] = p;
          ps += p;
        }
        ps = quad_sum(ps);
        lrow[ms][r] = lrow[ms][r] * alpha + ps;
#pragma unroll
        for (int n = 0; n < 8; ++n) O[ms][n][r] *= alpha;
      }
    __syncthreads();  // barrier C: all waves' QK sK-reads done before P overwrite
    // P write: swizzled [128][64] over sK; rows wave-private (same-wave RAW only)
#pragma unroll
    for (int ms = 0; ms < 2; ++ms)
#pragma unroll
      for (int ns = 0; ns < 4; ++ns)
#pragma unroll
        for (int r = 0; r < 4; ++r) {
          int row = w * 32 + ms * 16 + quad * 4 + r;
          int col = ns * 16 + lc;
          Pf[row * 64 + (((col >> 3) ^ (row & 7)) << 3) + (col & 7)] = f2bf(sc[ms][ns][r]);
        }
    // PV: A = P (own 32 rows), B = V^T from LDS (swizzled, ~2-way max)
#pragma unroll
    for (int kk2 = 0; kk2 < 2; ++kk2) {
      int r0 = w * 32 + lc, r1 = w * 32 + 16 + lc;
      short8 pa0 = *(const short8*)&Pf[r0 * 64 + (((kk2 * 4 + quad) ^ (r0 & 7)) << 3)];
      short8 pa1 = *(const short8*)&Pf[r1 * 64 + (((kk2 * 4 + quad) ^ (r1 & 7)) << 3)];
      short8 vb[8];
#pragma unroll
      for (int n = 0; n < 8; ++n) {
        int rr = n * 16 + lc;
        vb[n] = *(const short8*)&sV[rr * 64 + (((kk2 * 4 + quad) ^ (lc & 7)) << 3)];
      }
#pragma unroll
      for (int n = 0; n < 8; ++n) {
        O[0][n] = __builtin_amdgcn_mfma_f32_16x16x32_bf16(pa0, vb[n], O[0][n], 0, 0, 0);
        O[1][n] = __builtin_amdgcn_mfma_f32_16x16x32_bf16(pa1, vb[n], O[1][n], 0, 0, 0);
      }
    }
  }
  // epilogue: single-chunk (qt<4) normalize + write attn; else dump partials.
  if (nc == 1) {
#pragma unroll
    for (int ms = 0; ms < 2; ++ms)
#pragma unroll
      for (int r = 0; r < 4; ++r) {
        float inv = 1.0f / lrow[ms][r];
        int srow = qt * 128 + w * 32 + ms * 16 + quad * 4 + r;
        short* dst = attn + ((size_t)b * SS + srow) * 2048 + h * 128;
#pragma unroll
        for (int n = 0; n < 8; ++n)
          dst[n * 16 + lc] = f2bf(O[ms][n][r] * inv);
      }
  } else {
    float* Ob = Opart + (size_t)slot * 16384;
#pragma unroll
    for (int ms = 0; ms < 2; ++ms)
#pragma unroll
      for (int r = 0; r < 4; ++r) {
        int row = w * 32 + ms * 16 + quad * 4 + r;
#pragma unroll
        for (int n = 0; n < 8; ++n)
          Ob[(size_t)row * 128 + n * 16 + lc] = O[ms][n][r];
      }
    if (lc == 0) {
#pragma unroll
      for (int ms = 0; ms < 2; ++ms)
#pragma unroll
        for (int r = 0; r < 4; ++r) {
          int row = w * 32 + ms * 16 + quad * 4 + r;
          Mpart[slot * 128 + row] = mrow[ms][r];
          Lpart[slot * 128 + row] = lrow[ms][r];
        }
    }
  }
}

// ------------- combine split-K partials (qt>=4 only) -------------
// idx = ((bh*12 + (qt-4))*128 + r)*128 + col ; merges <=4 chunks per row.
__global__ __launch_bounds__(256) void combine_kernel(const float* __restrict__ Op,
                                                      const float* __restrict__ Mp,
                                                      const float* __restrict__ Lp,
                                                      short* __restrict__ attn) {
  int idx = blockIdx.x * 256 + threadIdx.x;   // 32*12*128*128 = 6291456
  int col = idx & 127;
  int r = (idx >> 7) & 127;
  int t = idx >> 14;                          // 0..383
  int bh = t / 12, qt = (t - bh * 12) + 4;
  int nc = (qt + 4) >> 2;
  int cbase;
  if (qt < 8)       cbase = 4 + 2 * (qt - 4);
  else if (qt < 12) cbase = 12 + 3 * (qt - 8);
  else              cbase = 24 + 4 * (qt - 12);
  int slot0 = bh * 40 + cbase;
  float mc[4];
#pragma unroll
  for (int cc = 0; cc < 4; ++cc)
    mc[cc] = (cc < nc) ? Mp[(size_t)(slot0 + cc) * 128 + r] : -1e30f;
  float M = fmaxf(fmaxf(mc[0], mc[1]), fmaxf(mc[2], mc[3]));
  float den = 0.f, acc = 0.f;
#pragma unroll
  for (int cc = 0; cc < 4; ++cc) {
    if (cc < nc) {
      float e = __expf(mc[cc] - M);
      den += e * Lp[(size_t)(slot0 + cc) * 128 + r];
      acc += e * Op[(size_t)(slot0 + cc) * 16384 + (size_t)r * 128 + col];
    }
  }
  int b = bh >> 4, hh = bh & 15;
  int srow = qt * 128 + r;
  attn[((size_t)b * SS + srow) * 2048 + hh * 128 + col] = f2bf(acc / den);
}

extern "C" void kernel_launch(void* const* d_in, const int* in_sizes, int n_in,
                              void* d_out, int out_size, void* d_ws, size_t ws_size,
                              hipStream_t stream) {
  const float* x   = (const float*)d_in[0];
  const float* Wkd = (const float*)d_in[1];
  const float* bkd = (const float*)d_in[2];
  const float* Wqd = (const float*)d_in[3];
  const float* bqd = (const float*)d_in[4];
  const float* Wku = (const float*)d_in[5];
  const float* bku = (const float*)d_in[6];
  const float* Wvu = (const float*)d_in[7];
  const float* bvu = (const float*)d_in[8];
  const float* Wqu = (const float*)d_in[9];
  const float* bqu = (const float*)d_in[10];
  const float* Wkr = (const float*)d_in[11];
  const float* bkr = (const float*)d_in[12];
  const float* Wqr = (const float*)d_in[13];
  const float* bqr = (const float*)d_in[14];
  const float* Wo  = (const float*)d_in[15];
  const float* bo  = (const float*)d_in[16];

  char* ws = (char*)d_ws;
  size_t off = 0;
  auto alloc = [&](size_t elems, size_t esz) -> void* {
    void* p = (void*)(ws + off);
    off += elems * esz;
    off = (off + 255) & ~(size_t)255;
    return p;
  };
  const int MS = BB * SS;  // 4096
  short* xb    = (short*)alloc((size_t)MS * DD, 2);
  short* cbuf  = (short*)alloc((size_t)MS * 3072, 2);   // kvc | qc | k_r
  short* qrbuf = (short*)alloc((size_t)MS * 1024, 2);
  short* vbuf  = (short*)alloc((size_t)MS * 2048, 2);   // UNUSED (kept: preserves the
                                                        // 93.3MB dead region Opart aliases)
  short* w1    = (short*)alloc((size_t)3072 * 2048, 2);  // [Wkd;Wqd;Wkr]
  short* w2    = (short*)alloc((size_t)3072 * 1536, 2);  // [Wqu;Wqr]
  short* w3    = (short*)alloc((size_t)4096 * 512, 2);   // [Wku;Wvu]
  short* wob   = (short*)alloc((size_t)2048 * 2048, 2);
  float* cb1   = (float*)alloc(3072, 4);
  float* cb2   = (float*)alloc(3072, 4);
  float* cb3   = (float*)alloc(4096, 4);
  short* qfull = (short*)alloc((size_t)BB * HH * SS * 192, 2);
  short* kfull = (short*)alloc((size_t)BB * HH * SS * 192, 2);
  short* vt    = (short*)alloc((size_t)BB * HH * DHH * SS, 2);
  short* attn  = (short*)alloc((size_t)MS * 2048, 2);
  if (off > ws_size) return;  // workspace too small: fail visibly

  // Split-K partials alias the xb..w3 region (93.3MB), dead once flash runs.
  // Opart 1280*16384*4 = 83.9MB, Mpart/Lpart 655KB each => 85.2MB < 93.3MB.
  float* Opart = (float*)ws;
  float* Mpart = (float*)(ws + (size_t)1280 * 16384 * 4);
  float* Lpart = (float*)(ws + (size_t)1280 * 16384 * 4 + (size_t)1280 * 128 * 4);

  auto cast = [&](const float* src, short* dst, size_t n) {
    int n4 = (int)(n >> 2);
    cast_bf16_kernel<<<dim3((unsigned)((n4 + 255) / 256)), dim3(256), 0, stream>>>(src, dst, n4);
  };
  cast(x,   xb, (size_t)MS * DD);
  cast(Wkd, w1,                          (size_t)512 * 2048);
  cast(Wqd, w1 + (size_t)512 * 2048,     (size_t)1536 * 2048);
  cast(Wkr, w1 + (size_t)2048 * 2048,    (size_t)1024 * 2048);
  cast(Wqu, w2,                          (size_t)2048 * 1536);
  cast(Wqr, w2 + (size_t)2048 * 1536,    (size_t)1024 * 1536);
  cast(Wku, w3,                          (size_t)2048 * 512);
  cast(Wvu, w3 + (size_t)2048 * 512,     (size_t)2048 * 512);
  cast(Wo,  wob,                         (size_t)2048 * 2048);
  concat_bias_kernel<<<dim3(40), dim3(256), 0, stream>>>(bkd, bqd, bkr, bqu, bqr, bku, bvu,
                                                         cb1, cb2, cb3);

  dim3 blk(256);
  // GEMM1: x @ [Wkd;Wqd;Wkr]^T -> cbuf [4096 x 3072] (kvc | qc | k_r)
  gemm_bt<0><<<dim3(32, 24), blk, 0, stream>>>(xb, DD, w1, DD, cb1, cbuf, nullptr,
                                               MS, 3072, DD);
  // GEMM2: qc @ [Wqu;Wqr]^T -> q_cnt scattered to qfull + q_r -> qrbuf
  gemm_bt<2><<<dim3(32, 24), blk, 0, stream>>>(cbuf + 512, 3072, w2, DCQ, cb2, qfull, qrbuf,
                                               MS, 3072, DCQ);
  // GEMM3: kvc @ [Wku;Wvu]^T -> k_cnt scattered to kfull + v -> vt (fused transpose)
  gemm_bt<3><<<dim3(32, 32), blk, 0, stream>>>(cbuf, 3072, w3, DCKV, cb3, kfull, vt,
                                               MS, 4096, DCKV);

  rope_kernel<<<dim3(BB * SS * HH * 32 / 256), blk, 0, stream>>>(qrbuf, 1024, 0, qfull);
  rope_kernel<<<dim3(BB * SS * HH * 32 / 256), blk, 0, stream>>>(cbuf, 3072, 2048, kfull);

  mla_flash_kernel<<<dim3(1280), blk, 0, stream>>>(qfull, kfull, vt, Opart, Mpart, Lpart, attn);
  combine_kernel<<<dim3(24576), blk, 0, stream>>>(Opart, Mpart, Lpart, attn);

  gemm_bt<1><<<dim3(32, 16), blk, 0, stream>>>(attn, DD, wob, DD, bo, d_out, nullptr,
                                               MS, DD, DD);
}

// Round 8
// 596.371 us; speedup vs baseline: 1.0591x; 1.0591x over previous
//
#include <hip/hip_runtime.h>
#include <stdint.h>
#include <stddef.h>

// MLA prefill: B=2,S=2048,D=2048,H=16,DH=128,DR=64,DCKV=512,DCQ=1536
#define BB 2
#define SS 2048
#define DD 2048
#define HH 16
#define DHH 128
#define DRR 64
#define DCKV 512
#define DCQ 1536

typedef __attribute__((ext_vector_type(8))) short short8;
typedef __attribute__((ext_vector_type(4))) short short4v;
typedef __attribute__((ext_vector_type(4))) float f32x4;
typedef unsigned int u32;

__device__ __forceinline__ short f2bf(float x) {
  unsigned u = __float_as_uint(x);
  u += 0x7fffu + ((u >> 16) & 1u);   // RNE
  return (short)(u >> 16);
}
__device__ __forceinline__ float bf2f(short s) {
  return __uint_as_float(((unsigned)(unsigned short)s) << 16);
}

// raw barrier: LDS writes visible (lgkmcnt 0) but global loads stay IN FLIGHT
// (no vmcnt drain — __syncthreads would emit s_waitcnt vmcnt(0) and serialize
// the prefetch every iteration; that drain was the R2-R7 invariant stall).
// Safe: in-flight globals write REGISTERS only — no cross-wave visibility issue.
#define BAR_NOVM() asm volatile("s_waitcnt lgkmcnt(0)\n\ts_barrier" ::: "memory")

// async global->LDS, 16B/lane: lds dest = wave-uniform base + lane*16.
__device__ __forceinline__ void gl2lds16(const short* g, short* l) {
  __builtin_amdgcn_global_load_lds(
      (const __attribute__((address_space(1))) u32*)g,
      (__attribute__((address_space(3))) u32*)l, 16, 0, 0);
}

// ---------------- cast fp32 -> bf16, x4 vectorized ----------------
__global__ __launch_bounds__(256) void cast_bf16_kernel(const float* __restrict__ in,
                                                        short* __restrict__ out, int n4) {
  int i = blockIdx.x * 256 + threadIdx.x;
  if (i >= n4) return;
  f32x4 f = ((const f32x4*)in)[i];
  short4v o;
  o[0] = f2bf(f[0]); o[1] = f2bf(f[1]); o[2] = f2bf(f[2]); o[3] = f2bf(f[3]);
  ((short4v*)out)[i] = o;
}

// ---------------- concat biases into cb1[3072], cb2[3072], cb3[4096] ----------------
__global__ __launch_bounds__(256) void concat_bias_kernel(
    const float* bkd, const float* bqd, const float* bkr,
    const float* bqu, const float* bqr, const float* bku, const float* bvu,
    float* cb1, float* cb2, float* cb3) {
  int idx = blockIdx.x * 256 + threadIdx.x;
  if (idx < 3072) {
    cb1[idx] = idx < 512 ? bkd[idx] : (idx < 2048 ? bqd[idx - 512] : bkr[idx - 2048]);
  } else if (idx < 6144) {
    int j = idx - 3072;
    cb2[j] = j < 2048 ? bqu[j] : bqr[j - 2048];
  } else if (idx < 10240) {
    int j = idx - 6144;
    cb3[j] = j < 2048 ? bku[j] : bvu[j - 2048];
  }
}

// ---------------- C[M,N] = A[M,K] @ B[N,K]^T + bias ----------------
// m97 structure: global_load_lds width-16 staging (linear LDS [row][32]),
// 2-barrier K-loop, 128x128 tile, BK=32, 4 waves (2x2 of 64x64).
// MODE 0: bf16 row-major.  MODE 1: f32 row-major.
// MODE 2: col<2048 scatter to qfull[B,H,S,192]; col>=2048 -> out2[row*1024+col-2048].
// MODE 3: col<2048 scatter to kfull[B,H,S,192]; col>=2048 -> FUSED TRANSPOSE into
//         vt[B,H,DH,S] (packed short4 along S) — replaces transpose_v pass.
template<int MODE>
__global__ __launch_bounds__(256) void gemm_bt(const short* __restrict__ A, int lda,
                                               const short* __restrict__ Bm, int ldb,
                                               const float* __restrict__ bias,
                                               void* __restrict__ Cout, void* __restrict__ out2,
                                               int M, int N, int K) {
  __shared__ __align__(16) short sA[128 * 32];
  __shared__ __align__(16) short sB[128 * 32];
  const int tid = threadIdx.x;
  const int w = tid >> 6, L = tid & 63, quad = L >> 4, lc = L & 15;
  const int wm = w >> 1, wn = w & 1;
  const int tm = blockIdx.x * 128, tn = blockIdx.y * 128;
  const int lrow = L >> 2, lch = (L & 3) * 8;
  f32x4 acc[4][4] = {};
  const int nk = K >> 5;
  for (int kt = 0; kt < nk; ++kt) {
    const int k0 = kt << 5;
    __syncthreads();
    {
      int sub = w * 2;
      gl2lds16(A + (size_t)(tm + sub * 16 + lrow) * lda + k0 + lch, &sA[sub * 512]);
      gl2lds16(A + (size_t)(tm + sub * 16 + 16 + lrow) * lda + k0 + lch, &sA[sub * 512 + 512]);
      gl2lds16(Bm + (size_t)(tn + sub * 16 + lrow) * ldb + k0 + lch, &sB[sub * 512]);
      gl2lds16(Bm + (size_t)(tn + sub * 16 + 16 + lrow) * ldb + k0 + lch, &sB[sub * 512 + 512]);
    }
    __syncthreads();
    short8 af[4], bfr[4];
#pragma unroll
    for (int ms = 0; ms < 4; ++ms)
      af[ms] = *(const short8*)&sA[(wm * 64 + ms * 16 + lc) * 32 + quad * 8];
#pragma unroll
    for (int ns = 0; ns < 4; ++ns)
      bfr[ns] = *(const short8*)&sB[(wn * 64 + ns * 16 + lc) * 32 + quad * 8];
#pragma unroll
    for (int ms = 0; ms < 4; ++ms)
#pragma unroll
      for (int ns = 0; ns < 4; ++ns)
        acc[ms][ns] = __builtin_amdgcn_mfma_f32_16x16x32_bf16(af[ms], bfr[ns], acc[ms][ns], 0, 0, 0);
  }
#pragma unroll
  for (int ms = 0; ms < 4; ++ms) {
    int row = tm + wm * 64 + ms * 16 + quad * 4;
#pragma unroll
    for (int ns = 0; ns < 4; ++ns) {
      int col = tn + wn * 64 + ns * 16 + lc;
      float bv = bias[col];
      if (MODE == 3 && col >= 2048) {
        // V -> vt[B,H,DH,S] fused transpose. row%4==0, so 4 r-values are 4
        // consecutive s at fixed (h_,dh): pack one 8B store.
        int j = col - 2048, h_ = j >> 7, dh = j & 127;
        int b_ = row >> 11, s0 = row & 2047;
        short4v pk;
#pragma unroll
        for (int r = 0; r < 4; ++r) pk[r] = f2bf(acc[ms][ns][r] + bv);
        *(short4v*)((short*)out2 + (((size_t)(b_ * HH + h_)) * DHH + dh) * SS + s0) = pk;
      } else {
#pragma unroll
        for (int r = 0; r < 4; ++r) {
          float vv = acc[ms][ns][r] + bv;
          int rrow = row + r;
          if (MODE == 0)      ((short*)Cout)[(size_t)rrow * N + col] = f2bf(vv);
          else if (MODE == 1) ((float*)Cout)[(size_t)rrow * N + col] = vv;
          else {
            if (col < 2048) {  // content -> full[B,H,S,192] (block-uniform branch)
              int b_ = rrow >> 11, s_ = rrow & 2047, h_ = col >> 7, d_ = col & 127;
              ((short*)Cout)[(((size_t)(b_ * HH + h_)) * SS + s_) * 192 + d_] = f2bf(vv);
            } else {  // MODE 2 only
              ((short*)out2)[(size_t)rrow * 1024 + (col - 2048)] = f2bf(vv);
            }
          }
        }
      }
    }
  }
}

// ------------- RoPE (rotate-half) into full[...,128:192]; strided bf16 src -------------
__global__ __launch_bounds__(256) void rope_kernel(const short* __restrict__ rin,
                                                   int rstride, int roff,
                                                   short* __restrict__ full) {
  int idx = blockIdx.x * 256 + threadIdx.x;  // B*S*H*32 threads
  int i = idx & 31, h = (idx >> 5) & 15, s = (idx >> 9) & 2047, b = idx >> 20;
  const short* base = rin + ((size_t)(b * SS + s)) * rstride + roff + h * DRR;
  float t1 = bf2f(base[i]), t2 = bf2f(base[i + 32]);
  float invf = expf(-9.210340371976184f * (float)i * (1.0f / 32.0f));  // 10000^(-i/32)
  float ang = (float)s * invf;
  float c = cosf(ang), sn = sinf(ang);
  short* ob = full + (((size_t)(b * HH + h)) * SS + s) * 192 + 128;
  ob[i]      = f2bf(t1 * c - t2 * sn);
  ob[i + 32] = f2bf(t1 * sn + t2 * c);
}

__device__ __forceinline__ float quad_max(float v) {
  v = fmaxf(v, __shfl_xor(v, 1));
  v = fmaxf(v, __shfl_xor(v, 2));
  v = fmaxf(v, __shfl_xor(v, 4));
  v = fmaxf(v, __shfl_xor(v, 8));
  return v;
}
__device__ __forceinline__ float quad_sum(float v) {
  v += __shfl_xor(v, 1); v += __shfl_xor(v, 2);
  v += __shfl_xor(v, 4); v += __shfl_xor(v, 8);
  return v;
}

// ------------- flash attention, SPLIT-K + RAW BARRIERS (R8) -------------
// R7 post-mortem: occupancy lever dead (unified-file regs ~230/wave cap at
// 2 waves/SIMD regardless of LDS); heavy-first raised FETCH 55->70MB. REVERTED
// both. The R2-R7 invariant stall identified: __syncthreads emits
// s_waitcnt vmcnt(0) before s_barrier, draining the prefetched K/V global
// loads EVERY iteration — ~25KB/block-iter of HBM fetch sat serially on the
// critical path (T_iter 6-9us vs ~1us of issue). R8 = R6 kernel (best, 203us)
// with both __syncthreads replaced by BAR_NOVM (lgkmcnt(0)+s_barrier, no vmcnt
// drain): kt+1 loads stay in flight across barriers; waited only by the
// ds_write at top of iter kt+1 (full QK+softmax+PV body of cover).
__global__ __launch_bounds__(256, 2) void mla_flash_kernel(const short* __restrict__ Qf,
                                                           const short* __restrict__ Kf,
                                                           const short* __restrict__ Vt,
                                                           float* __restrict__ Opart,
                                                           float* __restrict__ Mpart,
                                                           float* __restrict__ Lpart,
                                                           short* __restrict__ attn) {
  const int bid = blockIdx.x;
  const int g0 = (bid & 7) * 160 + (bid >> 3);  // bijective: XCD k serves bh in [4k,4k+4)
  const int bh = g0 / 40, xc = g0 - bh * 40;
  int qt, c;
  if (xc < 4)       { qt = xc;                  c = 0; }
  else if (xc < 12) { qt = 4 + ((xc - 4) >> 1);  c = (xc - 4) & 1; }
  else if (xc < 24) { qt = 8 + (xc - 12) / 3;    c = (xc - 12) % 3; }
  else              { qt = 12 + ((xc - 24) >> 2); c = (xc - 24) & 3; }
  const int nc = (qt + 4) >> 2;                 // chunks for this qt
  const int k8 = c * 8;                         // k-range in 64-col units
  const int klim = 2 * qt + 2;
  const int kend = (k8 + 8 < klim) ? k8 + 8 : klim;
  const int slot = bh * 40 + xc;                // compact partial slot

  const int h = bh & 15, b = bh >> 4;
  const int tid = threadIdx.x, w = tid >> 6, L = tid & 63, quad = L >> 4, lc = L & 15;
  __shared__ __align__(16) short sK[12288];     // 64x192 bf16 (XOR-swizzled), 24KB
  __shared__ __align__(16) short sV[8192];      // V^T tile [128dh][64s] swizzled, 16KB
  __shared__ __align__(16) short Pf[8192];      // P [128][64] bf16, 8-slot XOR swizzle, 16KB

  const short* Qb = Qf + ((size_t)bh) * SS * 192;
  const short* Kb = Kf + ((size_t)bh) * SS * 192;
  const short* Vb = Vt + ((size_t)bh) * DHH * SS;

  const int qrow0 = qt * 128 + w * 32;
  short8 qa[2][6];
#pragma unroll
  for (int ms = 0; ms < 2; ++ms)
#pragma unroll
    for (int kk = 0; kk < 6; ++kk)
      qa[ms][kk] = *(const short8*)(Qb + (size_t)(qrow0 + ms * 16 + lc) * 192 + kk * 32 + quad * 8);

  f32x4 O[2][8] = {};
  float mrow[2][4], lrow[2][4];
#pragma unroll
  for (int ms = 0; ms < 2; ++ms)
#pragma unroll
    for (int r = 0; r < 4; ++r) { mrow[ms][r] = -1e30f; lrow[ms][r] = 0.f; }

  // K staging map: thread stages row srow_=tid>>2, 16B chunk sq_=tid&3 of each
  // 32-col segment i (6 segs). Swizzled slot matches the QK read pattern.
  const int srow_ = tid >> 2, sq_ = tid & 3;
  const int sslot = srow_ * 4 + (sq_ ^ ((srow_ >> 1) & 3));
  // V staging map: thread stages rows j*32+(tid>>3), 16B chunk tid&7 (coalesced).
  const int vrow_ = tid >> 3, vch_ = tid & 7;
  short8 g[6], gv[4];
#pragma unroll
  for (int i = 0; i < 6; ++i)   // prologue: K tile k8
    g[i] = *(const short8*)(Kb + (size_t)(k8 * 64 + srow_) * 192 + i * 32 + sq_ * 8);
#pragma unroll
  for (int j = 0; j < 4; ++j)   // prologue: V tile k8
    gv[j] = *(const short8*)(Vb + (size_t)(j * 32 + vrow_) * SS + k8 * 64 + vch_ * 8);

  for (int kt = k8; kt < kend; ++kt) {
    BAR_NOVM();  // barrier A: all waves' prev-iter sK/sV reads done (no vmcnt drain)
    // ds_write staged tile kt (compiler inserts the vmcnt wait on g/gv here —
    // those loads have had a full iteration body to complete)
#pragma unroll
    for (int i = 0; i < 6; ++i)
      *(short8*)&sK[(i * 256 + sslot) * 8] = g[i];
#pragma unroll
    for (int j = 0; j < 4; ++j) {
      int row = j * 32 + vrow_;
      *(short8*)&sV[row * 64 + ((vch_ ^ (row & 7)) << 3)] = gv[j];
    }
    if (kt + 1 < kend) {   // issue next tile's loads; they stay in flight across BAR_NOVM
#pragma unroll
      for (int i = 0; i < 6; ++i)
        g[i] = *(const short8*)(Kb + (size_t)((kt + 1) * 64 + srow_) * 192 + i * 32 + sq_ * 8);
#pragma unroll
      for (int j = 0; j < 4; ++j)
        gv[j] = *(const short8*)(Vb + (size_t)(j * 32 + vrow_) * SS + (kt + 1) * 64 + vch_ * 8);
    }
    BAR_NOVM();  // barrier B: staging visible; prefetch NOT drained
    // QK: 64 k-cols
    f32x4 sc[2][4] = {};
#pragma unroll
    for (int kk = 0; kk < 6; ++kk)
#pragma unroll
      for (int ns = 0; ns < 4; ++ns) {
        int rr = ns * 16 + lc;
        short8 kb = *(const short8*)&sK[(kk * 256 + rr * 4 + (quad ^ ((rr >> 1) & 3))) * 8];
        sc[0][ns] = __builtin_amdgcn_mfma_f32_16x16x32_bf16(qa[0][kk], kb, sc[0][ns], 0, 0, 0);
        sc[1][ns] = __builtin_amdgcn_mfma_f32_16x16x32_bf16(qa[1][kk], kb, sc[1][ns], 0, 0, 0);
      }
    const float scale = 0.07216878364870322f;  // 1/sqrt(192)
#pragma unroll
    for (int ms = 0; ms < 2; ++ms)
#pragma unroll
      for (int ns = 0; ns < 4; ++ns)
#pragma unroll
        for (int r = 0; r < 4; ++r) {
          float vv = sc[ms][ns][r] * scale;
          if (kt * 64 + ns * 16 + lc > qrow0 + ms * 16 + quad * 4 + r) vv = -1e30f;
          sc[ms][ns][r] = vv;
        }
    // online softmax; row (ms, quad*4+r) lives in this quad's 16 lanes
#pragma unroll
    for (int ms = 0; ms < 2; ++ms)
#pragma unroll
      for (int r = 0; r < 4; ++r) {
        float mx = fmaxf(fmaxf(sc[ms][0][r], sc[ms][1][r]), fmaxf(sc[ms][2][r], sc[ms][3][r]));
        mx = quad_max(mx);
        float mnew = fmaxf(mrow[ms][r], mx);
        float alpha = __expf(mrow[ms][r] - mnew);
        mrow[ms][r] = mnew;
        float ps = 0.f;
#pragma unroll
        for (int ns = 0; ns < 4; ++ns) {
          float p = __expf(sc[ms][ns][r] - mnew);
          sc[ms][ns][r] = p;
          ps += p;
        }
        ps = quad_sum(ps);
        lrow[ms][r] = lrow[ms][r] * alpha + ps;
#pragma unroll
        for (int n = 0; n < 8; ++n) O[ms][n][r] *= alpha;
      }
    // P write: swizzled [128][64]; rows wave-private -> no barrier (same-wave RAW)
#pragma unroll
    for (int ms = 0; ms < 2; ++ms)
#pragma unroll
      for (int ns = 0; ns < 4; ++ns)
#pragma unroll
        for (int r = 0; r < 4; ++r) {
          int row = w * 32 + ms * 16 + quad * 4 + r;
          int col = ns * 16 + lc;
          Pf[row * 64 + (((col >> 3) ^ (row & 7)) << 3) + (col & 7)] = f2bf(sc[ms][ns][r]);
        }
    // PV: A = P (own 32 rows), B = V^T from LDS (swizzled, ~2-way max)
#pragma unroll
    for (int kk2 = 0; kk2 < 2; ++kk2) {
      int r0 = w * 32 + lc, r1 = w * 32 + 16 + lc;
      short8 pa0 = *(const short8*)&Pf[r0 * 64 + (((kk2 * 4 + quad) ^ (r0 & 7)) << 3)];
      short8 pa1 = *(const short8*)&Pf[r1 * 64 + (((kk2 * 4 + quad) ^ (r1 & 7)) << 3)];
      short8 vb[8];
#pragma unroll
      for (int n = 0; n < 8; ++n) {
        int rr = n * 16 + lc;
        vb[n] = *(const short8*)&sV[rr * 64 + (((kk2 * 4 + quad) ^ (lc & 7)) << 3)];
      }
#pragma unroll
      for (int n = 0; n < 8; ++n) {
        O[0][n] = __builtin_amdgcn_mfma_f32_16x16x32_bf16(pa0, vb[n], O[0][n], 0, 0, 0);
        O[1][n] = __builtin_amdgcn_mfma_f32_16x16x32_bf16(pa1, vb[n], O[1][n], 0, 0, 0);
      }
    }
  }
  // epilogue: single-chunk (qt<4) normalize + write attn; else dump partials.
  if (nc == 1) {
#pragma unroll
    for (int ms = 0; ms < 2; ++ms)
#pragma unroll
      for (int r = 0; r < 4; ++r) {
        float inv = 1.0f / lrow[ms][r];
        int srow = qt * 128 + w * 32 + ms * 16 + quad * 4 + r;
        short* dst = attn + ((size_t)b * SS + srow) * 2048 + h * 128;
#pragma unroll
        for (int n = 0; n < 8; ++n)
          dst[n * 16 + lc] = f2bf(O[ms][n][r] * inv);
      }
  } else {
    float* Ob = Opart + (size_t)slot * 16384;
#pragma unroll
    for (int ms = 0; ms < 2; ++ms)
#pragma unroll
      for (int r = 0; r < 4; ++r) {
        int row = w * 32 + ms * 16 + quad * 4 + r;
#pragma unroll
        for (int n = 0; n < 8; ++n)
          Ob[(size_t)row * 128 + n * 16 + lc] = O[ms][n][r];
      }
    if (lc == 0) {
#pragma unroll
      for (int ms = 0; ms < 2; ++ms)
#pragma unroll
        for (int r = 0; r < 4; ++r) {
          int row = w * 32 + ms * 16 + quad * 4 + r;
          Mpart[slot * 128 + row] = mrow[ms][r];
          Lpart[slot * 128 + row] = lrow[ms][r];
        }
    }
  }
}

// ------------- combine split-K partials (qt>=4 only) -------------
// idx = ((bh*12 + (qt-4))*128 + r)*128 + col ; merges <=4 chunks per row.
__global__ __launch_bounds__(256) void combine_kernel(const float* __restrict__ Op,
                                                      const float* __restrict__ Mp,
                                                      const float* __restrict__ Lp,
                                                      short* __restrict__ attn) {
  int idx = blockIdx.x * 256 + threadIdx.x;   // 32*12*128*128 = 6291456
  int col = idx & 127;
  int r = (idx >> 7) & 127;
  int t = idx >> 14;                          // 0..383
  int bh = t / 12, qt = (t - bh * 12) + 4;
  int nc = (qt + 4) >> 2;
  int cbase;
  if (qt < 8)       cbase = 4 + 2 * (qt - 4);
  else if (qt < 12) cbase = 12 + 3 * (qt - 8);
  else              cbase = 24 + 4 * (qt - 12);
  int slot0 = bh * 40 + cbase;
  float mc[4];
#pragma unroll
  for (int cc = 0; cc < 4; ++cc)
    mc[cc] = (cc < nc) ? Mp[(size_t)(slot0 + cc) * 128 + r] : -1e30f;
  float M = fmaxf(fmaxf(mc[0], mc[1]), fmaxf(mc[2], mc[3]));
  float den = 0.f, acc = 0.f;
#pragma unroll
  for (int cc = 0; cc < 4; ++cc) {
    if (cc < nc) {
      float e = __expf(mc[cc] - M);
      den += e * Lp[(size_t)(slot0 + cc) * 128 + r];
      acc += e * Op[(size_t)(slot0 + cc) * 16384 + (size_t)r * 128 + col];
    }
  }
  int b = bh >> 4, hh = bh & 15;
  int srow = qt * 128 + r;
  attn[((size_t)b * SS + srow) * 2048 + hh * 128 + col] = f2bf(acc / den);
}

extern "C" void kernel_launch(void* const* d_in, const int* in_sizes, int n_in,
                              void* d_out, int out_size, void* d_ws, size_t ws_size,
                              hipStream_t stream) {
  const float* x   = (const float*)d_in[0];
  const float* Wkd = (const float*)d_in[1];
  const float* bkd = (const float*)d_in[2];
  const float* Wqd = (const float*)d_in[3];
  const float* bqd = (const float*)d_in[4];
  const float* Wku = (const float*)d_in[5];
  const float* bku = (const float*)d_in[6];
  const float* Wvu = (const float*)d_in[7];
  const float* bvu = (const float*)d_in[8];
  const float* Wqu = (const float*)d_in[9];
  const float* bqu = (const float*)d_in[10];
  const float* Wkr = (const float*)d_in[11];
  const float* bkr = (const float*)d_in[12];
  const float* Wqr = (const float*)d_in[13];
  const float* bqr = (const float*)d_in[14];
  const float* Wo  = (const float*)d_in[15];
  const float* bo  = (const float*)d_in[16];

  char* ws = (char*)d_ws;
  size_t off = 0;
  auto alloc = [&](size_t elems, size_t esz) -> void* {
    void* p = (void*)(ws + off);
    off += elems * esz;
    off = (off + 255) & ~(size_t)255;
    return p;
  };
  const int MS = BB * SS;  // 4096
  short* xb    = (short*)alloc((size_t)MS * DD, 2);
  short* cbuf  = (short*)alloc((size_t)MS * 3072, 2);   // kvc | qc | k_r
  short* qrbuf = (short*)alloc((size_t)MS * 1024, 2);
  short* vbuf  = (short*)alloc((size_t)MS * 2048, 2);   // UNUSED (kept: preserves the
                                                        // 93.3MB dead region Opart aliases)
  short* w1    = (short*)alloc((size_t)3072 * 2048, 2);  // [Wkd;Wqd;Wkr]
  short* w2    = (short*)alloc((size_t)3072 * 1536, 2);  // [Wqu;Wqr]
  short* w3    = (short*)alloc((size_t)4096 * 512, 2);   // [Wku;Wvu]
  short* wob   = (short*)alloc((size_t)2048 * 2048, 2);
  float* cb1   = (float*)alloc(3072, 4);
  float* cb2   = (float*)alloc(3072, 4);
  float* cb3   = (float*)alloc(4096, 4);
  short* qfull = (short*)alloc((size_t)BB * HH * SS * 192, 2);
  short* kfull = (short*)alloc((size_t)BB * HH * SS * 192, 2);
  short* vt    = (short*)alloc((size_t)BB * HH * DHH * SS, 2);
  short* attn  = (short*)alloc((size_t)MS * 2048, 2);
  if (off > ws_size) return;  // workspace too small: fail visibly

  // Split-K partials alias the xb..w3 region (93.3MB), dead once flash runs.
  // Opart 1280*16384*4 = 83.9MB, Mpart/Lpart 655KB each => 85.2MB < 93.3MB.
  float* Opart = (float*)ws;
  float* Mpart = (float*)(ws + (size_t)1280 * 16384 * 4);
  float* Lpart = (float*)(ws + (size_t)1280 * 16384 * 4 + (size_t)1280 * 128 * 4);

  auto cast = [&](const float* src, short* dst, size_t n) {
    int n4 = (int)(n >> 2);
    cast_bf16_kernel<<<dim3((unsigned)((n4 + 255) / 256)), dim3(256), 0, stream>>>(src, dst, n4);
  };
  cast(x,   xb, (size_t)MS * DD);
  cast(Wkd, w1,                          (size_t)512 * 2048);
  cast(Wqd, w1 + (size_t)512 * 2048,     (size_t)1536 * 2048);
  cast(Wkr, w1 + (size_t)2048 * 2048,    (size_t)1024 * 2048);
  cast(Wqu, w2,                          (size_t)2048 * 1536);
  cast(Wqr, w2 + (size_t)2048 * 1536,    (size_t)1024 * 1536);
  cast(Wku, w3,                          (size_t)2048 * 512);
  cast(Wvu, w3 + (size_t)2048 * 512,     (size_t)2048 * 512);
  cast(Wo,  wob,                         (size_t)2048 * 2048);
  concat_bias_kernel<<<dim3(40), dim3(256), 0, stream>>>(bkd, bqd, bkr, bqu, bqr, bku, bvu,
                                                         cb1, cb2, cb3);

  dim3 blk(256);
  // GEMM1: x @ [Wkd;Wqd;Wkr]^T -> cbuf [4096 x 3072] (kvc | qc | k_r)
  gemm_bt<0><<<dim3(32, 24), blk, 0, stream>>>(xb, DD, w1, DD, cb1, cbuf, nullptr,
                                               MS, 3072, DD);
  // GEMM2: qc @ [Wqu;Wqr]^T -> q_cnt scattered to qfull + q_r -> qrbuf
  gemm_bt<2><<<dim3(32, 24), blk, 0, stream>>>(cbuf + 512, 3072, w2, DCQ, cb2, qfull, qrbuf,
                                               MS, 3072, DCQ);
  // GEMM3: kvc @ [Wku;Wvu]^T -> k_cnt scattered to kfull + v -> vt (fused transpose)
  gemm_bt<3><<<dim3(32, 32), blk, 0, stream>>>(cbuf, 3072, w3, DCKV, cb3, kfull, vt,
                                               MS, 4096, DCKV);

  rope_kernel<<<dim3(BB * SS * HH * 32 / 256), blk, 0, stream>>>(qrbuf, 1024, 0, qfull);
  rope_kernel<<<dim3(BB * SS * HH * 32 / 256), blk, 0, stream>>>(cbuf, 3072, 2048, kfull);

  mla_flash_kernel<<<dim3(1280), blk, 0, stream>>>(qfull, kfull, vt, Opart, Mpart, Lpart, attn);
  combine_kernel<<<dim3(24576), blk, 0, stream>>>(Opart, Mpart, Lpart, attn);

  gemm_bt<1><<<dim3(32, 16), blk, 0, stream>>>(attn, DD, wob, DD, bo, d_out, nullptr,
                                               MS, DD, DD);
}